// Round 5
// baseline (90.956 us; speedup 1.0000x reference)
//
#include <hip/hip_runtime.h>
#include <hip/hip_bf16.h>
#include <math.h>

// Point-major scatter + incremental exponential (R4), with the global-atomic
// merge replaced by coalesced partials (d_ws) + a contention-free column
// reduce. R4 post-mortem: ~128K global fp32 atomics contended 256-deep on 32
// cache lines were the largest controllable cost (~5 us of TCC RMW
// serialization); scatter itself is ~2 us.
//
// k1: 256 blocks x 512 thr, grid-stride points; LDS hist via ds_add_f32;
//     block row -> partials[block][512] (coalesced dword stores).
// k2: 512 blocks x 64 thr; block b sums column b of partials (L2-resident),
//     butterfly shuffle-reduce, out[b] = sum / r_b^2. Writes ALL bins, so no
//     memset dispatch is needed (d_out poison fully overwritten).
//
// Window math (absmax was 0.0 in R3/R4):
//  - bw > 0 always => weight <= 0 for r <= r0 - aw/bw: saturate clips EXACT 0.
//  - above r0 + 8*sigma: e <= 2^-46 -> skipped mass << 1e-12 absolute.
// Incremental exp drift ~1e-3 relative per contribution -> ~3e-8 abs on out
// (threshold 6.1e-7).

#define NBINS 512
#define TPB 512
#define NBLK 256
#define K_SQRT_HALF_PI 0.3989422804014327f   // sqrt(0.5/pi)
#define LOG2E 1.4426950408889634f

__device__ __forceinline__ float fast_exp2(float x) {
#if __has_builtin(__builtin_amdgcn_exp2f)
    return __builtin_amdgcn_exp2f(x);
#else
    return exp2f(x);
#endif
}

__global__ __launch_bounds__(TPB) void gauss_scatter(
    const float* __restrict__ means,
    const float* __restrict__ scan_point,
    const float* __restrict__ colours,
    const float* __restrict__ coeffs,
    const float* __restrict__ opac,
    const float* __restrict__ scales,
    const int* __restrict__ view_id,
    float* __restrict__ partials,    // [NBLK][NBINS]
    int n)
{
    __shared__ float hist[NBINS];
    const int t = threadIdx.x;
    hist[t] = 0.f;                               // TPB == NBINS
    __syncthreads();

    const int vid = view_id[0];                  // VIEW_NUM == 1
    const float sx = scan_point[0], sy = scan_point[1], sz = scan_point[2];

    for (int p = blockIdx.x * TPB + t; p < n; p += NBLK * TPB) {
        float dx = means[3 * p + 0] - sx;
        float dy = means[3 * p + 1] - sy;
        float dz = means[3 * p + 2] - sz;
        float r0 = sqrtf(fmaf(dx, dx, fmaf(dy, dy, dz * dz)));
        float sg = fmaxf(expf(scales[p]), 0.005f);   // max(exp(scales), BIN_RES/2)
        float inv_s = 1.0f / sg;
        float coeff = 1.0f / (1.0f + expf(-coeffs[p]));
        float op  = opac[p + vid];
        float col = colours[p];
        float ia  = (op * op) * (col * col) * 0.005f;    // intensity * BIN_RES/2
        float nalpha = 0.5f * LOG2E * inv_s * inv_s;     // exp2-units, positive
        float aw = ia * coeff * K_SQRT_HALF_PI * inv_s;  // pdf1 weight
        float bw = ia * (1.0f - coeff) * inv_s * inv_s;  // pdf2 weight (>0)

        float rlo = r0 - aw / bw;                    // exact w<=0 cutoff
        float rhi = fmaf(8.0f, sg, r0);              // e <= 2^-46 above
        int lo = (int)floorf(rlo * 200.f) - 1;       // bin b: r = 0.005*(b+1); slack bin
        int hi = (int)floorf(rhi * 200.f);
        lo = lo < 0 ? 0 : lo;
        hi = hi > NBINS - 1 ? NBINS - 1 : hi;
        if (lo > hi) continue;

        float diff0 = fmaf(0.005f, (float)(lo + 1), -r0);
        float e = fast_exp2(-(nalpha * diff0) * diff0);
        float d = fast_exp2(-nalpha * fmaf(0.01f, diff0, 2.5e-5f)); // -na*(2D*diff0+D^2)
        const float c = fast_exp2(-nalpha * 5.0e-5f);               // -2*na*D^2
        float w = fmaf(bw, diff0, aw);
        const float bwd = bw * 0.005f;
        for (int b = lo; b <= hi; ++b) {
            atomicAdd(&hist[b], __saturatef(e * w));  // ds_add_f32 no-return
            e *= d;
            d *= c;
            w += bwd;
        }
    }
    __syncthreads();

    partials[(size_t)blockIdx.x * NBINS + t] = hist[t];   // coalesced, no atomics
}

__global__ __launch_bounds__(64) void gauss_reduce(
    const float* __restrict__ partials, float* __restrict__ out)
{
    const int b = blockIdx.x;                    // one bin per block
    const int l = threadIdx.x;
    float acc = 0.f;
#pragma unroll
    for (int row = l; row < NBLK; row += 64)     // column read, L2-resident
        acc += partials[(size_t)row * NBINS + b];
#pragma unroll
    for (int off = 32; off > 0; off >>= 1)       // 64-lane butterfly
        acc += __shfl_xor(acc, off, 64);
    if (l == 0) {
        float r = 0.005f * (float)(b + 1);
        out[b] = acc / (r * r);                  // fold /r^DECAY (DECAY=2)
    }
}

extern "C" void kernel_launch(void* const* d_in, const int* in_sizes, int n_in,
                              void* d_out, int out_size, void* d_ws, size_t ws_size,
                              hipStream_t stream) {
    const float* means = (const float*)d_in[0];
    const float* scan  = (const float*)d_in[1];
    const float* col   = (const float*)d_in[2];
    const float* cf    = (const float*)d_in[3];
    const float* op    = (const float*)d_in[4];
    const float* sc    = (const float*)d_in[5];
    const int*   vid   = (const int*)d_in[6];
    float* out = (float*)d_out;
    float* partials = (float*)d_ws;              // 256*512*4 = 512 KB

    const int n = in_sizes[2];                   // colours: NUM_POINTS
    gauss_scatter<<<NBLK, TPB, 0, stream>>>(means, scan, col, cf, op, sc, vid, partials, n);
    gauss_reduce<<<NBINS, 64, 0, stream>>>(partials, out);
}

// Round 6
// 87.259 us; speedup vs baseline: 1.0424x; 1.0424x over previous
//
#include <hip/hip_runtime.h>
#include <hip/hip_bf16.h>
#include <math.h>

// Point-major scatter + incremental exponential, single kernel (R4 structure,
// the best measured: 88.5 us vs 91.0 for the partials+reduce split — the
// contended global atomic merge is CHEAPER than a transposed reduce pass).
// R6 refinement: stagger the merge bin index by blockIdx*16 (one 64B cache
// line per block) so the 256 blocks' lockstep merge atomics hit different L2
// lines at any instant instead of all hammering the same 4 lines per wave.
//
// Math (absmax 0.0 in R3-R5):
//  - contrib(b) = sat(e_b * (aw + bw*diff)), bw > 0 always, so weight <= 0
//    for r <= r0 - aw/bw: saturate clips to EXACT 0 -> exact lower cutoff.
//  - above r0 + 8*sigma: e <= 2^-46 -> skipped mass << 1e-12 absolute.
//  - uniform bin pitch D: e_{b+1} = e_b*d_b, d_{b+1} = d_b*c -> inner loop has
//    no transcendentals. Drift ~1e-3 relative -> ~3e-8 abs (thr 6.1e-7).
//  - upper clip at 1.0 provably inactive (pdf*D/2 <= 0.48) -> intensity folds.

#define NBINS 512
#define TPB 512
#define NBLK 256
#define K_SQRT_HALF_PI 0.3989422804014327f   // sqrt(0.5/pi)
#define LOG2E 1.4426950408889634f

__device__ __forceinline__ float fast_exp2(float x) {
#if __has_builtin(__builtin_amdgcn_exp2f)
    return __builtin_amdgcn_exp2f(x);
#else
    return exp2f(x);
#endif
}

__global__ __launch_bounds__(TPB) void gauss_scatter(
    const float* __restrict__ means,
    const float* __restrict__ scan_point,
    const float* __restrict__ colours,
    const float* __restrict__ coeffs,
    const float* __restrict__ opac,
    const float* __restrict__ scales,
    const int* __restrict__ view_id,
    float* __restrict__ out,
    int n)
{
    __shared__ float hist[NBINS];
    const int t = threadIdx.x;
    hist[t] = 0.f;                               // TPB == NBINS
    __syncthreads();

    const int vid = view_id[0];                  // VIEW_NUM == 1
    const float sx = scan_point[0], sy = scan_point[1], sz = scan_point[2];

    for (int p = blockIdx.x * TPB + t; p < n; p += NBLK * TPB) {
        float dx = means[3 * p + 0] - sx;
        float dy = means[3 * p + 1] - sy;
        float dz = means[3 * p + 2] - sz;
        float r0 = sqrtf(fmaf(dx, dx, fmaf(dy, dy, dz * dz)));
        float sg = fmaxf(expf(scales[p]), 0.005f);   // max(exp(scales), BIN_RES/2)
        float inv_s = 1.0f / sg;
        float coeff = 1.0f / (1.0f + expf(-coeffs[p]));
        float op  = opac[p + vid];
        float col = colours[p];
        float ia  = (op * op) * (col * col) * 0.005f;    // intensity * BIN_RES/2
        float nalpha = 0.5f * LOG2E * inv_s * inv_s;     // exp2-units, positive
        float aw = ia * coeff * K_SQRT_HALF_PI * inv_s;  // pdf1 weight
        float bw = ia * (1.0f - coeff) * inv_s * inv_s;  // pdf2 weight (>0)

        float rlo = r0 - aw / bw;                    // exact w<=0 cutoff
        float rhi = fmaf(8.0f, sg, r0);              // e <= 2^-46 above
        int lo = (int)floorf(rlo * 200.f) - 1;       // bin b: r = 0.005*(b+1); slack bin
        int hi = (int)floorf(rhi * 200.f);
        lo = lo < 0 ? 0 : lo;
        hi = hi > NBINS - 1 ? NBINS - 1 : hi;
        if (lo > hi) continue;

        float diff0 = fmaf(0.005f, (float)(lo + 1), -r0);
        float e = fast_exp2(-(nalpha * diff0) * diff0);
        float d = fast_exp2(-nalpha * fmaf(0.01f, diff0, 2.5e-5f)); // -na*(2D*diff0+D^2)
        const float c = fast_exp2(-nalpha * 5.0e-5f);               // -2*na*D^2
        float w = fmaf(bw, diff0, aw);
        const float bwd = bw * 0.005f;
        for (int b = lo; b <= hi; ++b) {
            atomicAdd(&hist[b], __saturatef(e * w));  // ds_add_f32 no-return
            e *= d;
            d *= c;
            w += bwd;
        }
    }
    __syncthreads();

    // merge: staggered by one cache line (16 bins) per block so concurrent
    // blocks hit different L2 lines; LDS read stays conflict-free.
    const int bin = (t + (blockIdx.x << 4)) & (NBINS - 1);
    float h = hist[bin];
    if (h != 0.f) {
        float r = 0.005f * (float)(bin + 1);
        atomicAdd(&out[bin], h / (r * r));           // fold /r^DECAY (DECAY=2)
    }
}

extern "C" void kernel_launch(void* const* d_in, const int* in_sizes, int n_in,
                              void* d_out, int out_size, void* d_ws, size_t ws_size,
                              hipStream_t stream) {
    const float* means = (const float*)d_in[0];
    const float* scan  = (const float*)d_in[1];
    const float* col   = (const float*)d_in[2];
    const float* cf    = (const float*)d_in[3];
    const float* op    = (const float*)d_in[4];
    const float* sc    = (const float*)d_in[5];
    const int*   vid   = (const int*)d_in[6];
    float* out = (float*)d_out;

    const int n = in_sizes[2];                       // colours: NUM_POINTS
    hipMemsetAsync(d_out, 0, (size_t)out_size * sizeof(float), stream);
    gauss_scatter<<<NBLK, TPB, 0, stream>>>(means, scan, col, cf, op, sc, vid, out, n);
}